// Round 11
// baseline (163.974 us; speedup 1.0000x reference)
//
#include <hip/hip_runtime.h>
#include <hip/hip_bf16.h>
#include <hip/hip_cooperative_groups.h>

namespace cg = cooperative_groups;

#define B_ 8
#define DIN 16
#define L_ 4096
#define D_ 512
#define NP 4104
#define NG 342
#define JSP 32
#define JCH 129
#define SPAN 48
#define NSPAN 86

__device__ __forceinline__ unsigned short f2bf(float f) {
  unsigned int u = __float_as_uint(f);
  unsigned int r = (u + 0x7fffu + ((u >> 16) & 1u)) >> 16;
  return (unsigned short)r;
}
__device__ __forceinline__ float bf2f(unsigned int u) {
  return __uint_as_float(u << 16);
}

// degree-5 Taylor of e^t about t0=0.525, raw monomial basis; valid [0,1.05], err<=1e-4
__device__ __constant__ float D5[6] = {0.9999544f, 1.0005163f, 0.4975827f,
                                       0.1726558f, 0.0334570f, 0.0140872f};
__device__ __constant__ float FACT[6] = {1.f, 1.f, 2.f, 6.f, 24.f, 120.f};

// ================= cooperative chain: uprep -> scores -> moment -> apply =================
// grid 256 x 256. LDS pool reused per phase. grid.sync() between phases.
__global__ __launch_bounds__(256) void k_chain(
    const float* __restrict__ x, const float* __restrict__ cw,
    const float* __restrict__ cb, const float* __restrict__ sw,
    const float* __restrict__ sb, unsigned short* __restrict__ s0,
    float* __restrict__ Mpart, float* __restrict__ us, float* __restrict__ s2) {
  cg::grid_group grid = cg::this_grid();
  __shared__ float pool[3648];
  int t = threadIdx.x;
  int vb = blockIdx.x;

  // ---- phase 0: us[0..63] = u, us[64] = c0 (65 blocks) ----
  if (vb < 65) {
    float sv_;
    if (vb < 64)
      sv_ = sw[t] * cw[((size_t)t << 6) + vb] +
            sw[t + 256] * cw[((size_t)(t + 256) << 6) + vb];
    else
      sv_ = sw[t] * cb[t] + sw[t + 256] * cb[t + 256];
    pool[t] = sv_;
    __syncthreads();
    if (t < 64) pool[t] += pool[t + 64] + pool[t + 128] + pool[t + 192];
    __syncthreads();
    if (t == 0) {
      float s = 0.f;
      for (int j = 0; j < 64; ++j) s += pool[j];
      us[vb] = s;
    }
  }
  grid.sync();

  // ---- phase 1: scores -> softmax over m -> s0 (176 virtual blocks of 192 thr) ----
  if (vb < 176) {
    float* xs = pool;          // 3120
    float* ul = pool + 3120;   // 65
    float* tb = pool + 3200;   // 192
    int b = vb / 22, blk = vb - b * 22;
    int base0 = blk * 192;
    const float* xb = x + (size_t)b * DIN * L_;
    for (int q = t; q < DIN * 195; q += 256) {
      int i = q / 195, c = q - i * 195;
      int nx = base0 - 1 + c;
      xs[q] = (nx >= 0 && nx < L_) ? xb[i * L_ + nx] : 0.f;
    }
    if (t < 65) ul[t] = us[t];
    __syncthreads();
    if (t < 192) {
      int n = base0 + t;
      float tv = 0.f;
      if (n < L_) {
        tv = ul[64];
        for (int i = 0; i < DIN; ++i) {
#pragma unroll
          for (int k = 0; k < 4; ++k)
            tv = fmaf(xs[i * 195 + t + k], ul[(i << 2) + k], tv);
        }
      }
      tb[t] = tv;
    }
    __syncthreads();
    if (t < 192) {
      int n = base0 + t;
      if (n < NP) {
        float t1 = tb[t];
        int e2 = t & ~1;
        float t2 = 0.5f * (tb[e2] + tb[e2 + 1]);
        int e3 = (t / 3) * 3;
        float t3 = (1.f / 3.f) * (tb[e3] + tb[e3 + 1] + tb[e3 + 2]);
        int e4 = t & ~3;
        float t4 = 0.25f * (tb[e4] + tb[e4 + 1] + tb[e4 + 2] + tb[e4 + 3]);
        float sbv = sb[0];
        float c0s = t1 + sbv, c1s = t2 + sbv, c2s = t3 + sbv, c3s = t4 + sbv;
        float mx = fmaxf(fmaxf(c0s, c1s), fmaxf(c2s, c3s));
        float e0 = __expf(c0s - mx), e1 = __expf(c1s - mx);
        float e2f = __expf(c2s - mx), e3f = __expf(c3s - mx);
        float inv = 1.f / (e0 + e1 + e2f + e3f);
        ushort4 ov;
        ov.x = f2bf(e0 * inv); ov.y = f2bf(e1 * inv);
        ov.z = f2bf(e2f * inv); ov.w = f2bf(e3f * inv);
        *reinterpret_cast<ushort4*>(&s0[(((size_t)b * NP) + n) << 2]) = ov;
      }
    }
  }
  grid.sync();

  // ---- phase 2: moment accumulation, weights folded (256 blocks) ----
  {
    float (*sv)[4] = (float(*)[4])(pool);        // 516
    float (*ls)[4] = (float(*)[4])(pool + 520);  // 516
    float* mp = pool + 1040;                     // 2560
    int js = vb & 31;
    int b = vb >> 5;
    int lane = t & 63, wv = t >> 6;
    int jlo = js * JCH;
    int cnt = NP - jlo; if (cnt > JCH) cnt = JCH;
    const ushort4* sp = reinterpret_cast<const ushort4*>(s0) + (size_t)b * NP + jlo;
    for (int r = t; r < cnt; r += 256) {
      ushort4 u = sp[r];
      float v0 = bf2f(u.x), v1 = bf2f(u.y), v2 = bf2f(u.z), v3 = bf2f(u.w);
      sv[r][0] = v0; sv[r][1] = v1; sv[r][2] = v2; sv[r][3] = v3;
      ls[r][0] = __log2f(v0); ls[r][1] = __log2f(v1);
      ls[r][2] = __log2f(v2); ls[r][3] = __log2f(v3);
    }
    int f1 = lane, f2 = lane + 64;
    float e1a = 0.f, e1b = 0.f, e1c = 0.f, e1d = 0.f;
    float e2a = 0.f, e2b = 0.f, e2c = 0.f, e2d = 0.f;
    {
      int f = 0;
      for (int a = 0; a <= 5; ++a)
        for (int b2 = 0; b2 <= 5 - a; ++b2)
          for (int c = 0; c <= 5 - a - b2; ++c)
            for (int d2 = 0; d2 <= 5 - a - b2 - c; ++d2) {
              if (f == f1) { e1a = a; e1b = b2; e1c = c; e1d = d2; }
              if (f == f2) { e2a = a; e2b = b2; e2c = c; e2d = d2; }
              ++f;
            }
    }
    __syncthreads();
    float acc1[5] = {0.f, 0.f, 0.f, 0.f, 0.f};
    float acc2[5] = {0.f, 0.f, 0.f, 0.f, 0.f};
    for (int jj = wv; jj < cnt; jj += 4) {
      float4 lv = *reinterpret_cast<float4*>(&ls[jj][0]);
      float4 vv = *reinterpret_cast<float4*>(&sv[jj][0]);
      float t1 = e1a * lv.x;
      t1 = fmaf(e1b, lv.y, t1);
      t1 = fmaf(e1c, lv.z, t1);
      t1 = fmaf(e1d, lv.w, t1);
      float t2 = e2a * lv.x;
      t2 = fmaf(e2b, lv.y, t2);
      t2 = fmaf(e2c, lv.z, t2);
      t2 = fmaf(e2d, lv.w, t2);
      float m1 = exp2f(t1);
      float m2 = exp2f(t2);
      acc1[0] = fmaf(m1, vv.x, acc1[0]);
      acc1[1] = fmaf(m1, vv.y, acc1[1]);
      acc1[2] = fmaf(m1, vv.z, acc1[2]);
      acc1[3] = fmaf(m1, vv.w, acc1[3]);
      acc1[4] += m1;
      acc2[0] = fmaf(m2, vv.x, acc2[0]);
      acc2[1] = fmaf(m2, vv.y, acc2[1]);
      acc2[2] = fmaf(m2, vv.z, acc2[2]);
      acc2[3] = fmaf(m2, vv.w, acc2[3]);
      acc2[4] += m2;
    }
    __syncthreads();
#pragma unroll
    for (int c = 0; c < 5; ++c) {
      mp[wv * 640 + lane * 5 + c] = acc1[c];
      mp[wv * 640 + (lane + 64) * 5 + c] = acc2[c];
    }
    __syncthreads();
    if (t < 630) {
      int f = t / 5, c = t - f * 5;
      float s = mp[f * 5 + c] + mp[640 + f * 5 + c] + mp[1280 + f * 5 + c] +
                mp[1920 + f * 5 + c];
      int fa = 0, fb = 0, fc = 0, fd = 0;
      {
        int ff = 0;
        for (int a = 0; a <= 5; ++a)
          for (int b2 = 0; b2 <= 5 - a; ++b2)
            for (int cc = 0; cc <= 5 - a - b2; ++cc)
              for (int d2 = 0; d2 <= 5 - a - b2 - cc; ++d2) {
                if (ff == f) { fa = a; fb = b2; fc = cc; fd = d2; }
                ++ff;
              }
      }
      int k = fa + fb + fc + fd;
      float w = D5[k] * FACT[k] / (FACT[fa] * FACT[fb] * FACT[fc] * FACT[fd]);
      Mpart[((size_t)(b * 32 + js)) * 640 + t] = w * s;
    }
  }
  grid.sync();

  // ---- phase 3: apply -> s2 (136 virtual blocks) ----
  if (vb < 136) {
    float* M = pool;  // 1024
    int b = vb / 17, ch = vb - b * 17;
    for (int e = t; e < 630; e += 256) {
      float s = 0.f;
#pragma unroll 4
      for (int js = 0; js < JSP; ++js)
        s += Mpart[((size_t)(b * 32 + js)) * 640 + e];
      int f = e / 5, c = e - f * 5;
      M[f * 8 + c] = s;
    }
    __syncthreads();
    int i = ch * 256 + t;
    if (i < NP) {
      ushort4 u = reinterpret_cast<const ushort4*>(s0)[(size_t)b * NP + i];
      float s_0 = bf2f(u.x), s_1 = bf2f(u.y), s_2 = bf2f(u.z), s_3 = bf2f(u.w);
      float a0 = 0.f, a1 = 0.f, a2 = 0.f, a3 = 0.f, az = 0.f;
      int f = 0;
      float pa = 1.f;
#pragma unroll
      for (int a = 0; a <= 5; ++a) {
        float pb = pa;
#pragma unroll
        for (int b2 = 0; b2 <= 5 - a; ++b2) {
          float pc = pb;
#pragma unroll
          for (int c = 0; c <= 5 - a - b2; ++c) {
            float run = pc;
#pragma unroll
            for (int d2 = 0; d2 <= 5 - a - b2 - c; ++d2) {
              const float* mf = &M[f * 8];
              float4 m4 = *reinterpret_cast<const float4*>(mf);
              a0 = fmaf(run, m4.x, a0);
              a1 = fmaf(run, m4.y, a1);
              a2 = fmaf(run, m4.z, a2);
              a3 = fmaf(run, m4.w, a3);
              az = fmaf(run, mf[4], az);
              run *= s_3;
              ++f;
            }
            pc *= s_2;
          }
          pb *= s_1;
        }
        pa *= s_0;
      }
      float inv = 1.f / az;
      reinterpret_cast<float4*>(s2)[(size_t)b * NP + i] =
          make_float4(a0 * inv, a1 * inv, a2 * inv, a3 * inv);
    }
  }
}

// ================= fallback copies of the split chain (used only if coop launch fails) =================
__global__ __launch_bounds__(256) void k_uprep(
    const float* __restrict__ cw, const float* __restrict__ cb,
    const float* __restrict__ sw, float* __restrict__ us) {
  __shared__ float red[4][64];
  __shared__ float red2[64];
  int t = threadIdx.x;
  int p = t & 63, chunk = t >> 6;
  float s = 0.f;
  for (int d = chunk * 128; d < chunk * 128 + 128; ++d)
    s = fmaf(sw[d], cw[((size_t)d << 6) + p], s);
  red[chunk][p] = s;
  if (t < 64) {
    float pc = 0.f;
    for (int j = 0; j < 8; ++j) pc = fmaf(sw[t + 64 * j], cb[t + 64 * j], pc);
    red2[t] = pc;
  }
  __syncthreads();
  if (t < 64) us[t] = red[0][t] + red[1][t] + red[2][t] + red[3][t];
  if (t == 0) {
    float c0 = 0.f;
    for (int j = 0; j < 64; ++j) c0 += red2[j];
    us[64] = c0;
  }
}

__global__ __launch_bounds__(192) void k_scores(
    const float* __restrict__ x, const float* __restrict__ us,
    const float* __restrict__ sb, unsigned short* __restrict__ s0) {
  __shared__ float xs[DIN * 195];
  __shared__ float ul[65];
  __shared__ float tb[192];
  int bid = blockIdx.x;
  int b = bid / 22, blk = bid - b * 22;
  int base0 = blk * 192;
  int t = threadIdx.x;
  const float* xb = x + (size_t)b * DIN * L_;
  for (int q = t; q < DIN * 195; q += 192) {
    int i = q / 195, c = q - i * 195;
    int nx = base0 - 1 + c;
    xs[q] = (nx >= 0 && nx < L_) ? xb[i * L_ + nx] : 0.f;
  }
  if (t < 65) ul[t] = us[t];
  __syncthreads();
  int n = base0 + t;
  float tv = 0.f;
  if (n < L_) {
    tv = ul[64];
    for (int i = 0; i < DIN; ++i) {
#pragma unroll
      for (int k = 0; k < 4; ++k)
        tv = fmaf(xs[i * 195 + t + k], ul[(i << 2) + k], tv);
    }
  }
  tb[t] = tv;
  __syncthreads();
  if (n < NP) {
    float t1 = tb[t];
    int e2 = t & ~1;
    float t2 = 0.5f * (tb[e2] + tb[e2 + 1]);
    int e3 = (t / 3) * 3;
    float t3 = (1.f / 3.f) * (tb[e3] + tb[e3 + 1] + tb[e3 + 2]);
    int e4 = t & ~3;
    float t4 = 0.25f * (tb[e4] + tb[e4 + 1] + tb[e4 + 2] + tb[e4 + 3]);
    float sbv = sb[0];
    float c0s = t1 + sbv, c1s = t2 + sbv, c2s = t3 + sbv, c3s = t4 + sbv;
    float mx = fmaxf(fmaxf(c0s, c1s), fmaxf(c2s, c3s));
    float e0 = __expf(c0s - mx), e1 = __expf(c1s - mx);
    float e2f = __expf(c2s - mx), e3f = __expf(c3s - mx);
    float inv = 1.f / (e0 + e1 + e2f + e3f);
    ushort4 ov;
    ov.x = f2bf(e0 * inv); ov.y = f2bf(e1 * inv);
    ov.z = f2bf(e2f * inv); ov.w = f2bf(e3f * inv);
    *reinterpret_cast<ushort4*>(&s0[(((size_t)b * NP) + n) << 2]) = ov;
  }
}

__global__ __launch_bounds__(256) void k_moment(
    const unsigned short* __restrict__ s0, float* __restrict__ Mpart) {
  __shared__ float sv[JCH][4];
  __shared__ float ls[JCH][4];
  __shared__ float mp[4][128][5];
  int bid = blockIdx.x;
  int js = bid & 31;
  int b = bid >> 5;
  int t = threadIdx.x;
  int lane = t & 63, wv = t >> 6;
  int jlo = js * JCH;
  int cnt = NP - jlo; if (cnt > JCH) cnt = JCH;
  const ushort4* sp = reinterpret_cast<const ushort4*>(s0) + (size_t)b * NP + jlo;
  for (int r = t; r < cnt; r += 256) {
    ushort4 u = sp[r];
    float v0 = bf2f(u.x), v1 = bf2f(u.y), v2 = bf2f(u.z), v3 = bf2f(u.w);
    sv[r][0] = v0; sv[r][1] = v1; sv[r][2] = v2; sv[r][3] = v3;
    ls[r][0] = __log2f(v0); ls[r][1] = __log2f(v1);
    ls[r][2] = __log2f(v2); ls[r][3] = __log2f(v3);
  }
  int f1 = lane, f2 = lane + 64;
  float e1a = 0.f, e1b = 0.f, e1c = 0.f, e1d = 0.f;
  float e2a = 0.f, e2b = 0.f, e2c = 0.f, e2d = 0.f;
  {
    int f = 0;
    for (int a = 0; a <= 5; ++a)
      for (int b2 = 0; b2 <= 5 - a; ++b2)
        for (int c = 0; c <= 5 - a - b2; ++c)
          for (int d2 = 0; d2 <= 5 - a - b2 - c; ++d2) {
            if (f == f1) { e1a = a; e1b = b2; e1c = c; e1d = d2; }
            if (f == f2) { e2a = a; e2b = b2; e2c = c; e2d = d2; }
            ++f;
          }
  }
  __syncthreads();
  float acc1[5] = {0.f, 0.f, 0.f, 0.f, 0.f};
  float acc2[5] = {0.f, 0.f, 0.f, 0.f, 0.f};
  for (int jj = wv; jj < cnt; jj += 4) {
    float4 lv = *reinterpret_cast<float4*>(&ls[jj][0]);
    float4 vv = *reinterpret_cast<float4*>(&sv[jj][0]);
    float t1 = e1a * lv.x;
    t1 = fmaf(e1b, lv.y, t1);
    t1 = fmaf(e1c, lv.z, t1);
    t1 = fmaf(e1d, lv.w, t1);
    float t2 = e2a * lv.x;
    t2 = fmaf(e2b, lv.y, t2);
    t2 = fmaf(e2c, lv.z, t2);
    t2 = fmaf(e2d, lv.w, t2);
    float m1 = exp2f(t1);
    float m2 = exp2f(t2);
    acc1[0] = fmaf(m1, vv.x, acc1[0]);
    acc1[1] = fmaf(m1, vv.y, acc1[1]);
    acc1[2] = fmaf(m1, vv.z, acc1[2]);
    acc1[3] = fmaf(m1, vv.w, acc1[3]);
    acc1[4] += m1;
    acc2[0] = fmaf(m2, vv.x, acc2[0]);
    acc2[1] = fmaf(m2, vv.y, acc2[1]);
    acc2[2] = fmaf(m2, vv.z, acc2[2]);
    acc2[3] = fmaf(m2, vv.w, acc2[3]);
    acc2[4] += m2;
  }
#pragma unroll
  for (int c = 0; c < 5; ++c) {
    mp[wv][lane][c] = acc1[c];
    mp[wv][lane + 64][c] = acc2[c];
  }
  __syncthreads();
  if (t < 630) {
    int f = t / 5, c = t - f * 5;
    float s = mp[0][f][c] + mp[1][f][c] + mp[2][f][c] + mp[3][f][c];
    int fa = 0, fb = 0, fc = 0, fd = 0;
    {
      int ff = 0;
      for (int a = 0; a <= 5; ++a)
        for (int b2 = 0; b2 <= 5 - a; ++b2)
          for (int cc = 0; cc <= 5 - a - b2; ++cc)
            for (int d2 = 0; d2 <= 5 - a - b2 - cc; ++d2) {
              if (ff == f) { fa = a; fb = b2; fc = cc; fd = d2; }
              ++ff;
            }
    }
    int k = fa + fb + fc + fd;
    float w = D5[k] * FACT[k] / (FACT[fa] * FACT[fb] * FACT[fc] * FACT[fd]);
    Mpart[((size_t)(b * 32 + js)) * 640 + t] = w * s;
  }
}

__global__ __launch_bounds__(256) void k_apply(
    const unsigned short* __restrict__ s0, const float* __restrict__ Mpart,
    float* __restrict__ s2) {
  __shared__ float M[128 * 8];
  int bid = blockIdx.x;
  int b = bid / 17, ch = bid - b * 17;
  int t = threadIdx.x;
  for (int e = t; e < 630; e += 256) {
    float s = 0.f;
#pragma unroll 4
    for (int js = 0; js < JSP; ++js)
      s += Mpart[((size_t)(b * 32 + js)) * 640 + e];
    int f = e / 5, c = e - f * 5;
    M[f * 8 + c] = s;
  }
  __syncthreads();
  int i = ch * 256 + t;
  if (i >= NP) return;
  ushort4 u = reinterpret_cast<const ushort4*>(s0)[(size_t)b * NP + i];
  float s_0 = bf2f(u.x), s_1 = bf2f(u.y), s_2 = bf2f(u.z), s_3 = bf2f(u.w);
  float a0 = 0.f, a1 = 0.f, a2 = 0.f, a3 = 0.f, az = 0.f;
  int f = 0;
  float pa = 1.f;
#pragma unroll
  for (int a = 0; a <= 5; ++a) {
    float pb = pa;
#pragma unroll
    for (int b2 = 0; b2 <= 5 - a; ++b2) {
      float pc = pb;
#pragma unroll
      for (int c = 0; c <= 5 - a - b2; ++c) {
        float run = pc;
#pragma unroll
        for (int d2 = 0; d2 <= 5 - a - b2 - c; ++d2) {
          const float* mf = &M[f * 8];
          float4 m4 = *reinterpret_cast<const float4*>(mf);
          a0 = fmaf(run, m4.x, a0);
          a1 = fmaf(run, m4.y, a1);
          a2 = fmaf(run, m4.z, a2);
          a3 = fmaf(run, m4.w, a3);
          az = fmaf(run, mf[4], az);
          run *= s_3;
          ++f;
        }
        pc *= s_2;
      }
      pb *= s_1;
    }
    pa *= s_0;
  }
  float inv = 1.f / az;
  reinterpret_cast<float4*>(s2)[(size_t)b * NP + i] =
      make_float4(a0 * inv, a1 * inv, a2 * inv, a3 * inv);
}

// ---------------- Kernel 4: fused conv + pooled-combine -> outputs (round-6 exact) ----------------
__global__ __launch_bounds__(256, 4) void k_fused(
    const float* __restrict__ x, const float* __restrict__ cw,
    const float* __restrict__ cb, const float* __restrict__ s2,
    float* __restrict__ out) {
  __shared__ float ws_w[64 * 132];   // 33792 B
  __shared__ float ws_x[DIN * 52];   // 3328 B
  __shared__ float ss[4][12][4];     // 768 B
  int bid = blockIdx.x;
  int dtile = bid & 3;
  int span = (bid >> 2) % NSPAN;
  int b = bid / (4 * NSPAN);
  int n0 = span * SPAN;
  int d0 = dtile * 128;
  int g0 = n0 / 12;
  int tid = threadIdx.x;

  for (int q = tid; q < 128 * 16; q += 256) {
    int dd = q >> 4, qq = (q & 15) << 2;
    float4 wv = *reinterpret_cast<const float4*>(cw + ((size_t)(d0 + dd) << 6) + qq);
    *reinterpret_cast<float4*>(&ws_w[(dd >> 1) * 132 + (dd & 1) * 64 + qq]) = wv;
  }
  const float* xb = x + (size_t)b * DIN * L_;
  for (int q = tid; q < DIN * 52; q += 256) {
    int i = q / 52, c = q - i * 52;
    int nx = n0 - 1 + c;
    ws_x[q] = (c < 51 && nx >= 0 && nx < L_) ? xb[i * L_ + nx] : 0.f;
  }
  if (tid < 192) {
    int gg = tid / 48, r = tid - gg * 48;
    int g = g0 + gg;
    ((float*)ss)[tid] = (g < NG) ? s2[((size_t)b * NP + g * 12) * 4 + r] : 0.f;
  }
  __syncthreads();

  int dp = tid & 63;
  int seg = tid >> 6;
  int g = g0 + seg;
  float acc0[12], acc1[12];
#pragma unroll
  for (int j = 0; j < 12; ++j) { acc0[j] = 0.f; acc1[j] = 0.f; }

  for (int i = 0; i < DIN; ++i) {
    const float* wp = &ws_w[dp * 132 + (i << 2)];
    float4 wv0 = *reinterpret_cast<const float4*>(wp);
    float4 wv1 = *reinterpret_cast<const float4*>(wp + 64);
    const float* xp = &ws_x[i * 52 + seg * 12];
    float4 xv0 = *reinterpret_cast<const float4*>(xp);
    float4 xv1 = *reinterpret_cast<const float4*>(xp + 4);
    float4 xv2 = *reinterpret_cast<const float4*>(xp + 8);
    float4 xv3 = *reinterpret_cast<const float4*>(xp + 12);
    float xr[16] = {xv0.x, xv0.y, xv0.z, xv0.w, xv1.x, xv1.y, xv1.z, xv1.w,
                    xv2.x, xv2.y, xv2.z, xv2.w, xv3.x, xv3.y, xv3.z, xv3.w};
#pragma unroll
    for (int j = 0; j < 12; ++j) {
      float a0 = acc0[j], a1 = acc1[j];
      a0 = fmaf(wv0.x, xr[j], a0);
      a0 = fmaf(wv0.y, xr[j + 1], a0);
      a0 = fmaf(wv0.z, xr[j + 2], a0);
      a0 = fmaf(wv0.w, xr[j + 3], a0);
      a1 = fmaf(wv1.x, xr[j], a1);
      a1 = fmaf(wv1.y, xr[j + 1], a1);
      a1 = fmaf(wv1.z, xr[j + 2], a1);
      a1 = fmaf(wv1.w, xr[j + 3], a1);
      acc0[j] = a0; acc1[j] = a1;
    }
  }
  if (g >= NG) return;

  int d = d0 + (dp << 1);
  float cb0 = cb[d], cb1 = cb[d + 1];
  int base = g * 12;
  float hv0[12], hv1[12];
#pragma unroll
  for (int j = 0; j < 12; ++j) {
    int n = base + j;
    if (n < L_) { hv0[j] = acc0[j] + cb0; hv1[j] = acc1[j] + cb1; }
    else { hv0[j] = 0.f; hv1[j] = 0.f; }
  }
  float P20[6], P21[6], P30[4], P31[4], P40[3], P41[3];
#pragma unroll
  for (int q = 0; q < 6; ++q) {
    P20[q] = 0.5f * (hv0[2 * q] + hv0[2 * q + 1]);
    P21[q] = 0.5f * (hv1[2 * q] + hv1[2 * q + 1]);
  }
#pragma unroll
  for (int q = 0; q < 4; ++q) {
    P30[q] = (1.f / 3.f) * (hv0[3 * q] + hv0[3 * q + 1] + hv0[3 * q + 2]);
    P31[q] = (1.f / 3.f) * (hv1[3 * q] + hv1[3 * q + 1] + hv1[3 * q + 2]);
  }
#pragma unroll
  for (int q = 0; q < 3; ++q) {
    P40[q] = 0.25f * (hv0[4 * q] + hv0[4 * q + 1] + hv0[4 * q + 2] + hv0[4 * q + 3]);
    P41[q] = 0.25f * (hv1[4 * q] + hv1[4 * q + 1] + hv1[4 * q + 2] + hv1[4 * q + 3]);
  }
  float* outc = out;
  float* outd = out + (size_t)B_ * L_ * D_;
  float xq0[3] = {0.f, 0.f, 0.f}, xq1[3] = {0.f, 0.f, 0.f};
#pragma unroll
  for (int j = 0; j < 12; ++j) {
    float w0 = ss[seg][j][0], w1 = ss[seg][j][1];
    float w2 = ss[seg][j][2], w3 = ss[seg][j][3];
    float v0 = w0 * hv0[j] + w1 * P20[j >> 1] + w2 * P30[j / 3] + w3 * P40[j >> 2];
    float v1 = w0 * hv1[j] + w1 * P21[j >> 1] + w2 * P31[j / 3] + w3 * P41[j >> 2];
    int n = base + j;
    if (n < L_) {
      float2 o; o.x = v0; o.y = v1;
      *reinterpret_cast<float2*>(&outc[((size_t)b * L_ + n) * D_ + d]) = o;
    }
    xq0[j >> 2] += v0; xq1[j >> 2] += v1;
  }
#pragma unroll
  for (int q = 0; q < 3; ++q) {
    int r = 3 * g + q;
    if (r < 1024) {
      float2 o; o.x = 0.25f * xq0[q]; o.y = 0.25f * xq1[q];
      *reinterpret_cast<float2*>(&outd[((size_t)b * 1024 + r) * D_ + d]) = o;
    }
  }
}

extern "C" void kernel_launch(void* const* d_in, const int* in_sizes, int n_in,
                              void* d_out, int out_size, void* d_ws, size_t ws_size,
                              hipStream_t stream) {
  const float* x = (const float*)d_in[0];
  const float* cw = (const float*)d_in[1];
  const float* cb = (const float*)d_in[2];
  const float* sw = (const float*)d_in[3];
  const float* sb = (const float*)d_in[4];
  float* out = (float*)d_out;
  char* ws = (char*)d_ws;
  size_t off = 0;
  unsigned short* s0 = (unsigned short*)(ws + off);        // 262,656 B
  off += 262656;
  float* s2 = (float*)(ws + off);                          // 525,312 B
  off += 525312;
  float* Mpart = (float*)(ws + off);                       // 655,360 B
  off += 655360;
  float* us = (float*)(ws + off);                          // 260 B

  void* args[] = {(void*)&x, (void*)&cw, (void*)&cb, (void*)&sw, (void*)&sb,
                  (void*)&s0, (void*)&Mpart, (void*)&us, (void*)&s2};
  hipError_t cerr = hipLaunchCooperativeKernel((const void*)k_chain, dim3(256),
                                               dim3(256), args, 0, stream);
  if (cerr != hipSuccess) {
    // fallback: classic split chain
    k_uprep<<<1, 256, 0, stream>>>(cw, cb, sw, us);
    k_scores<<<8 * 22, 192, 0, stream>>>(x, us, sb, s0);
    k_moment<<<B_ * JSP, 256, 0, stream>>>(s0, Mpart);
    k_apply<<<B_ * 17, 256, 0, stream>>>(s0, Mpart, s2);
  }
  k_fused<<<B_ * NSPAN * 4, 256, 0, stream>>>(x, cw, cb, s2, out);
}

// Round 13
// 77.743 us; speedup vs baseline: 2.1092x; 2.1092x over previous
//
#include <hip/hip_runtime.h>
#include <hip/hip_bf16.h>

#define B_ 8
#define DIN 16
#define L_ 4096
#define D_ 512
#define NP 4104
#define NG 342
#define JSP 32
#define JCH 129
#define SPAN2 96
#define NSPAN2 43
#define XSTR 104

__device__ __forceinline__ unsigned short f2bf(float f) {
  unsigned int u = __float_as_uint(f);
  unsigned int r = (u + 0x7fffu + ((u >> 16) & 1u)) >> 16;
  return (unsigned short)r;
}
__device__ __forceinline__ float bf2f(unsigned int u) {
  return __uint_as_float(u << 16);
}

// degree-5 Taylor of e^t about t0=0.525, raw monomial basis; valid [0,1.05], err<=1e-4
__device__ __constant__ float D5[6] = {0.9999544f, 1.0005163f, 0.4975827f,
                                       0.1726558f, 0.0334570f, 0.0140872f};
__device__ __constant__ float FACT[6] = {1.f, 1.f, 2.f, 6.f, 24.f, 120.f};

// ---------------- Kernel 0: u prep (1 block) ----------------
__global__ __launch_bounds__(256) void k_uprep(
    const float* __restrict__ cw, const float* __restrict__ cb,
    const float* __restrict__ sw, float* __restrict__ us) {
  __shared__ float red[4][64];
  __shared__ float red2[64];
  int t = threadIdx.x;
  int p = t & 63, chunk = t >> 6;
  float s = 0.f;
  for (int d = chunk * 128; d < chunk * 128 + 128; ++d)
    s = fmaf(sw[d], cw[((size_t)d << 6) + p], s);
  red[chunk][p] = s;
  if (t < 64) {
    float pc = 0.f;
    for (int j = 0; j < 8; ++j) pc = fmaf(sw[t + 64 * j], cb[t + 64 * j], pc);
    red2[t] = pc;
  }
  __syncthreads();
  if (t < 64) us[t] = red[0][t] + red[1][t] + red[2][t] + red[3][t];
  if (t == 0) {
    float c0 = 0.f;
    for (int j = 0; j < 64; ++j) c0 += red2[j];
    us[64] = c0;
  }
}

// ---------------- Kernel 1: scores -> softmax over m -> s0 (bf16) ----------------
__global__ __launch_bounds__(192) void k_scores(
    const float* __restrict__ x, const float* __restrict__ us,
    const float* __restrict__ sb, unsigned short* __restrict__ s0) {
  __shared__ float xs[DIN * 195];
  __shared__ float ul[65];
  __shared__ float tb[192];
  int bid = blockIdx.x;
  int b = bid / 22, blk = bid - b * 22;
  int base0 = blk * 192;
  int t = threadIdx.x;
  const float* xb = x + (size_t)b * DIN * L_;
  for (int q = t; q < DIN * 195; q += 192) {
    int i = q / 195, c = q - i * 195;
    int nx = base0 - 1 + c;
    xs[q] = (nx >= 0 && nx < L_) ? xb[i * L_ + nx] : 0.f;
  }
  if (t < 65) ul[t] = us[t];
  __syncthreads();
  int n = base0 + t;
  float tv = 0.f;
  if (n < L_) {
    tv = ul[64];
    for (int i = 0; i < DIN; ++i) {
#pragma unroll
      for (int k = 0; k < 4; ++k)
        tv = fmaf(xs[i * 195 + t + k], ul[(i << 2) + k], tv);
    }
  }
  tb[t] = tv;
  __syncthreads();
  if (n < NP) {
    float t1 = tb[t];
    int e2 = t & ~1;
    float t2 = 0.5f * (tb[e2] + tb[e2 + 1]);
    int e3 = (t / 3) * 3;
    float t3 = (1.f / 3.f) * (tb[e3] + tb[e3 + 1] + tb[e3 + 2]);
    int e4 = t & ~3;
    float t4 = 0.25f * (tb[e4] + tb[e4 + 1] + tb[e4 + 2] + tb[e4 + 3]);
    float sbv = sb[0];
    float c0s = t1 + sbv, c1s = t2 + sbv, c2s = t3 + sbv, c3s = t4 + sbv;
    float mx = fmaxf(fmaxf(c0s, c1s), fmaxf(c2s, c3s));
    float e0 = __expf(c0s - mx), e1 = __expf(c1s - mx);
    float e2f = __expf(c2s - mx), e3f = __expf(c3s - mx);
    float inv = 1.f / (e0 + e1 + e2f + e3f);
    ushort4 ov;
    ov.x = f2bf(e0 * inv); ov.y = f2bf(e1 * inv);
    ov.z = f2bf(e2f * inv); ov.w = f2bf(e3f * inv);
    *reinterpret_cast<ushort4*>(&s0[(((size_t)b * NP) + n) << 2]) = ov;
  }
}

// ---------------- Kernel 2: moment accumulation ----------------
__global__ __launch_bounds__(256) void k_moment(
    const unsigned short* __restrict__ s0, float* __restrict__ Mpart) {
  __shared__ float sv[JCH][4];
  __shared__ float ls[JCH][4];
  __shared__ float mp[4][128][5];
  int bid = blockIdx.x;
  int js = bid & 31;
  int b = bid >> 5;
  int t = threadIdx.x;
  int lane = t & 63, wv = t >> 6;
  int jlo = js * JCH;
  int cnt = NP - jlo; if (cnt > JCH) cnt = JCH;

  const ushort4* sp = reinterpret_cast<const ushort4*>(s0) + (size_t)b * NP + jlo;
  for (int r = t; r < cnt; r += 256) {
    ushort4 u = sp[r];
    float v0 = bf2f(u.x), v1 = bf2f(u.y), v2 = bf2f(u.z), v3 = bf2f(u.w);
    sv[r][0] = v0; sv[r][1] = v1; sv[r][2] = v2; sv[r][3] = v3;
    ls[r][0] = __log2f(v0); ls[r][1] = __log2f(v1);
    ls[r][2] = __log2f(v2); ls[r][3] = __log2f(v3);
  }
  int f1 = lane, f2 = lane + 64;
  float e1a = 0.f, e1b = 0.f, e1c = 0.f, e1d = 0.f;
  float e2a = 0.f, e2b = 0.f, e2c = 0.f, e2d = 0.f;
  {
    int f = 0;
    for (int a = 0; a <= 5; ++a)
      for (int b2 = 0; b2 <= 5 - a; ++b2)
        for (int c = 0; c <= 5 - a - b2; ++c)
          for (int d2 = 0; d2 <= 5 - a - b2 - c; ++d2) {
            if (f == f1) { e1a = a; e1b = b2; e1c = c; e1d = d2; }
            if (f == f2) { e2a = a; e2b = b2; e2c = c; e2d = d2; }
            ++f;
          }
  }
  __syncthreads();
  float acc1[5] = {0.f, 0.f, 0.f, 0.f, 0.f};
  float acc2[5] = {0.f, 0.f, 0.f, 0.f, 0.f};
  for (int jj = wv; jj < cnt; jj += 4) {
    float4 lv = *reinterpret_cast<float4*>(&ls[jj][0]);
    float4 vv = *reinterpret_cast<float4*>(&sv[jj][0]);
    float t1 = e1a * lv.x;
    t1 = fmaf(e1b, lv.y, t1);
    t1 = fmaf(e1c, lv.z, t1);
    t1 = fmaf(e1d, lv.w, t1);
    float t2 = e2a * lv.x;
    t2 = fmaf(e2b, lv.y, t2);
    t2 = fmaf(e2c, lv.z, t2);
    t2 = fmaf(e2d, lv.w, t2);
    float m1 = exp2f(t1);
    float m2 = exp2f(t2);
    acc1[0] = fmaf(m1, vv.x, acc1[0]);
    acc1[1] = fmaf(m1, vv.y, acc1[1]);
    acc1[2] = fmaf(m1, vv.z, acc1[2]);
    acc1[3] = fmaf(m1, vv.w, acc1[3]);
    acc1[4] += m1;
    acc2[0] = fmaf(m2, vv.x, acc2[0]);
    acc2[1] = fmaf(m2, vv.y, acc2[1]);
    acc2[2] = fmaf(m2, vv.z, acc2[2]);
    acc2[3] = fmaf(m2, vv.w, acc2[3]);
    acc2[4] += m2;
  }
#pragma unroll
  for (int c = 0; c < 5; ++c) {
    mp[wv][lane][c] = acc1[c];
    mp[wv][lane + 64][c] = acc2[c];
  }
  __syncthreads();
  if (t < 630) {
    int f = t / 5, c = t - f * 5;
    float s = mp[0][f][c] + mp[1][f][c] + mp[2][f][c] + mp[3][f][c];
    Mpart[((size_t)(b * 32 + js)) * 640 + t] = s;
  }
}

// ---------------- Kernel 3: reduce partials, fold weights -> Mfin[b][128][8] ----------------
__global__ __launch_bounds__(640) void k_mred(
    const float* __restrict__ Mpart, float* __restrict__ Mfin) {
  int b = blockIdx.x;
  int t = threadIdx.x;
  if (t >= 630) return;
  int f = t / 5, c = t - f * 5;
  float s = 0.f;
  for (int js = 0; js < JSP; ++js)
    s += Mpart[((size_t)(b * 32 + js)) * 640 + t];
  int fa = 0, fb = 0, fc = 0, fd = 0;
  {
    int ff = 0;
    for (int a = 0; a <= 5; ++a)
      for (int b2 = 0; b2 <= 5 - a; ++b2)
        for (int cc = 0; cc <= 5 - a - b2; ++cc)
          for (int d2 = 0; d2 <= 5 - a - b2 - cc; ++d2) {
            if (ff == f) { fa = a; fb = b2; fc = cc; fd = d2; }
            ++ff;
          }
  }
  int k = fa + fb + fc + fd;
  float w = D5[k] * FACT[k] / (FACT[fa] * FACT[fb] * FACT[fc] * FACT[fd]);
  Mfin[((size_t)b * 128 + f) * 8 + c] = w * s;
}

// ---------------- Kernel 4: apply -> s2[b][i][4] ----------------
__global__ __launch_bounds__(256) void k_apply(
    const unsigned short* __restrict__ s0, const float* __restrict__ Mfin,
    float* __restrict__ s2) {
  __shared__ float M[128 * 8];
  int bid = blockIdx.x;
  int b = bid / 17, ch = bid - b * 17;
  int t = threadIdx.x;
  const float4* Mb = reinterpret_cast<const float4*>(Mfin + (size_t)b * 128 * 8);
  if (t < 252) *reinterpret_cast<float4*>(&M[t * 4]) = Mb[t];
  __syncthreads();
  int i = ch * 256 + t;
  if (i >= NP) return;
  ushort4 u = reinterpret_cast<const ushort4*>(s0)[(size_t)b * NP + i];
  float s_0 = bf2f(u.x), s_1 = bf2f(u.y), s_2 = bf2f(u.z), s_3 = bf2f(u.w);
  float a0 = 0.f, a1 = 0.f, a2 = 0.f, a3 = 0.f, az = 0.f;
  int f = 0;
  float pa = 1.f;
#pragma unroll
  for (int a = 0; a <= 5; ++a) {
    float pb = pa;
#pragma unroll
    for (int b2 = 0; b2 <= 5 - a; ++b2) {
      float pc = pb;
#pragma unroll
      for (int c = 0; c <= 5 - a - b2; ++c) {
        float run = pc;
#pragma unroll
        for (int d2 = 0; d2 <= 5 - a - b2 - c; ++d2) {
          const float* mf = &M[f * 8];
          float4 m4 = *reinterpret_cast<const float4*>(mf);
          a0 = fmaf(run, m4.x, a0);
          a1 = fmaf(run, m4.y, a1);
          a2 = fmaf(run, m4.z, a2);
          a3 = fmaf(run, m4.w, a3);
          az = fmaf(run, mf[4], az);
          run *= s_3;
          ++f;
        }
        pc *= s_2;
      }
      pb *= s_1;
    }
    pa *= s_0;
  }
  float inv = 1.f / az;
  reinterpret_cast<float4*>(s2)[(size_t)b * NP + i] =
      make_float4(a0 * inv, a1 * inv, a2 * inv, a3 * inv);
}

// ---------------- Kernel 5: fused conv + pooled-combine -> outputs ----------------
// 64 d x 96 n per block (LDS 25 KB -> 6 blocks/CU).
// block 256 = 32 d-pairs x 8 groups-of-12. grid: b(8) x span(43) x dtile(8).
__global__ __launch_bounds__(256, 4) void k_fused(
    const float* __restrict__ x, const float* __restrict__ cw,
    const float* __restrict__ cb, const float* __restrict__ s2,
    float* __restrict__ out) {
  __shared__ float ws_w[32 * 132];      // 16896 B
  __shared__ float ws_x[DIN * XSTR];    // 6656 B
  __shared__ float ss[8][12][4];        // 1536 B
  int bid = blockIdx.x;
  int dtile = bid & 7;
  int span = (bid >> 3) % NSPAN2;
  int b = bid / (8 * NSPAN2);
  int n0 = span * SPAN2;
  int d0 = dtile * 64;
  int g0 = n0 / 12;
  int tid = threadIdx.x;

  for (int q = tid; q < 64 * 16; q += 256) {
    int dd = q >> 4, qq = (q & 15) << 2;
    float4 wv = *reinterpret_cast<const float4*>(cw + ((size_t)(d0 + dd) << 6) + qq);
    *reinterpret_cast<float4*>(&ws_w[(dd >> 1) * 132 + (dd & 1) * 64 + qq]) = wv;
  }
  const float* xb = x + (size_t)b * DIN * L_;
  for (int q = tid; q < DIN * XSTR; q += 256) {
    int i = q / XSTR, c = q - i * XSTR;
    int nx = n0 - 1 + c;
    ws_x[q] = (c < 99 && nx >= 0 && nx < L_) ? xb[i * L_ + nx] : 0.f;
  }
  for (int q = tid; q < 384; q += 256) {   // FIXED: grid-stride, fills all 8 groups
    int gg = q / 48, r = q - gg * 48;
    int g = g0 + gg;
    ((float*)ss)[q] = (g < NG) ? s2[((size_t)b * NP + g * 12) * 4 + r] : 0.f;
  }
  __syncthreads();

  int dp = tid & 31;
  int seg = tid >> 5;
  int g = g0 + seg;
  float acc0[12], acc1[12];
#pragma unroll
  for (int j = 0; j < 12; ++j) { acc0[j] = 0.f; acc1[j] = 0.f; }

  for (int i = 0; i < DIN; ++i) {
    const float* wp = &ws_w[dp * 132 + (i << 2)];
    float4 wv0 = *reinterpret_cast<const float4*>(wp);
    float4 wv1 = *reinterpret_cast<const float4*>(wp + 64);
    const float* xp = &ws_x[i * XSTR + seg * 12];
    float4 xv0 = *reinterpret_cast<const float4*>(xp);
    float4 xv1 = *reinterpret_cast<const float4*>(xp + 4);
    float4 xv2 = *reinterpret_cast<const float4*>(xp + 8);
    float4 xv3 = *reinterpret_cast<const float4*>(xp + 12);
    float xr[16] = {xv0.x, xv0.y, xv0.z, xv0.w, xv1.x, xv1.y, xv1.z, xv1.w,
                    xv2.x, xv2.y, xv2.z, xv2.w, xv3.x, xv3.y, xv3.z, xv3.w};
#pragma unroll
    for (int j = 0; j < 12; ++j) {
      float a0 = acc0[j], a1 = acc1[j];
      a0 = fmaf(wv0.x, xr[j], a0);
      a0 = fmaf(wv0.y, xr[j + 1], a0);
      a0 = fmaf(wv0.z, xr[j + 2], a0);
      a0 = fmaf(wv0.w, xr[j + 3], a0);
      a1 = fmaf(wv1.x, xr[j], a1);
      a1 = fmaf(wv1.y, xr[j + 1], a1);
      a1 = fmaf(wv1.z, xr[j + 2], a1);
      a1 = fmaf(wv1.w, xr[j + 3], a1);
      acc0[j] = a0; acc1[j] = a1;
    }
  }
  if (g >= NG) return;

  int d = d0 + (dp << 1);
  float cb0 = cb[d], cb1 = cb[d + 1];
  int base = g * 12;
  float hv0[12], hv1[12];
#pragma unroll
  for (int j = 0; j < 12; ++j) {
    int n = base + j;
    if (n < L_) { hv0[j] = acc0[j] + cb0; hv1[j] = acc1[j] + cb1; }
    else { hv0[j] = 0.f; hv1[j] = 0.f; }
  }
  float P20[6], P21[6], P30[4], P31[4], P40[3], P41[3];
#pragma unroll
  for (int q = 0; q < 6; ++q) {
    P20[q] = 0.5f * (hv0[2 * q] + hv0[2 * q + 1]);
    P21[q] = 0.5f * (hv1[2 * q] + hv1[2 * q + 1]);
  }
#pragma unroll
  for (int q = 0; q < 4; ++q) {
    P30[q] = (1.f / 3.f) * (hv0[3 * q] + hv0[3 * q + 1] + hv0[3 * q + 2]);
    P31[q] = (1.f / 3.f) * (hv1[3 * q] + hv1[3 * q + 1] + hv1[3 * q + 2]);
  }
#pragma unroll
  for (int q = 0; q < 3; ++q) {
    P40[q] = 0.25f * (hv0[4 * q] + hv0[4 * q + 1] + hv0[4 * q + 2] + hv0[4 * q + 3]);
    P41[q] = 0.25f * (hv1[4 * q] + hv1[4 * q + 1] + hv1[4 * q + 2] + hv1[4 * q + 3]);
  }
  float* outc = out;
  float* outd = out + (size_t)B_ * L_ * D_;
  float xq0[3] = {0.f, 0.f, 0.f}, xq1[3] = {0.f, 0.f, 0.f};
#pragma unroll
  for (int j = 0; j < 12; ++j) {
    float w0 = ss[seg][j][0], w1 = ss[seg][j][1];
    float w2 = ss[seg][j][2], w3 = ss[seg][j][3];
    float v0 = w0 * hv0[j] + w1 * P20[j >> 1] + w2 * P30[j / 3] + w3 * P40[j >> 2];
    float v1 = w0 * hv1[j] + w1 * P21[j >> 1] + w2 * P31[j / 3] + w3 * P41[j >> 2];
    int n = base + j;
    if (n < L_) {
      float2 o; o.x = v0; o.y = v1;
      *reinterpret_cast<float2*>(&outc[((size_t)b * L_ + n) * D_ + d]) = o;
    }
    xq0[j >> 2] += v0; xq1[j >> 2] += v1;
  }
#pragma unroll
  for (int q = 0; q < 3; ++q) {
    int r = 3 * g + q;
    if (r < 1024) {
      float2 o; o.x = 0.25f * xq0[q]; o.y = 0.25f * xq1[q];
      *reinterpret_cast<float2*>(&outd[((size_t)b * 1024 + r) * D_ + d]) = o;
    }
  }
}

extern "C" void kernel_launch(void* const* d_in, const int* in_sizes, int n_in,
                              void* d_out, int out_size, void* d_ws, size_t ws_size,
                              hipStream_t stream) {
  const float* x = (const float*)d_in[0];
  const float* cw = (const float*)d_in[1];
  const float* cb = (const float*)d_in[2];
  const float* sw = (const float*)d_in[3];
  const float* sb = (const float*)d_in[4];
  float* out = (float*)d_out;
  char* ws = (char*)d_ws;
  size_t off = 0;
  unsigned short* s0 = (unsigned short*)(ws + off);        // 262,656 B
  off += 262656;
  float* s2 = (float*)(ws + off);                          // 525,312 B
  off += 525312;
  float* Mpart = (float*)(ws + off);                       // 655,360 B
  off += 655360;
  float* Mfin = (float*)(ws + off);                        // 32,768 B
  off += 32768;
  float* us = (float*)(ws + off);                          // 260 B

  k_uprep<<<1, 256, 0, stream>>>(cw, cb, sw, us);
  k_scores<<<8 * 22, 192, 0, stream>>>(x, us, sb, s0);
  k_moment<<<B_ * JSP, 256, 0, stream>>>(s0, Mpart);
  k_mred<<<B_, 640, 0, stream>>>(Mpart, Mfin);
  k_apply<<<B_ * 17, 256, 0, stream>>>(s0, Mfin, s2);
  k_fused<<<B_ * NSPAN2 * 8, 256, 0, stream>>>(x, cw, cb, s2, out);
}

// Round 14
// 77.340 us; speedup vs baseline: 2.1202x; 1.0052x over previous
//
#include <hip/hip_runtime.h>
#include <hip/hip_bf16.h>

#define B_ 8
#define DIN 16
#define L_ 4096
#define D_ 512
#define NP 4104
#define NG 342
#define NCH 44
#define SPAN2 96
#define NSPAN2 43
#define XSTR 104

__device__ __forceinline__ unsigned short f2bf(float f) {
  unsigned int u = __float_as_uint(f);
  unsigned int r = (u + 0x7fffu + ((u >> 16) & 1u)) >> 16;
  return (unsigned short)r;
}
__device__ __forceinline__ float bf2f(unsigned int u) {
  return __uint_as_float(u << 16);
}

// degree-5 Taylor of e^t about t0=0.525, raw monomial basis; valid [0,1.05], err<=1e-4
__device__ __constant__ float D5[6] = {0.9999544f, 1.0005163f, 0.4975827f,
                                       0.1726558f, 0.0334570f, 0.0140872f};
__device__ __constant__ float FACT[6] = {1.f, 1.f, 2.f, 6.f, 24.f, 120.f};

// ---------------- Kernel 1: u-prep + scores + softmax + moment partials ----------------
// grid: b(8) x blk(22); block 256. Writes s0 (bf16 softmax rows) and Mpart (44 chunks/b,
// weighted). u computed per-block with WAVE-COALESCED cw reads (lane = fast dim).
__global__ __launch_bounds__(256) void k_scores2(
    const float* __restrict__ x, const float* __restrict__ cw,
    const float* __restrict__ cb, const float* __restrict__ sw,
    const float* __restrict__ sb, unsigned short* __restrict__ s0,
    float* __restrict__ Mpart) {
  __shared__ float xs[DIN * 195];
  __shared__ float ured[4][65];
  __shared__ float ul[65];
  __shared__ float tb[192];
  __shared__ __align__(16) float sval[192][5];
  __shared__ __align__(16) float lsv[192][4];
  int bid = blockIdx.x;
  int b = bid / 22, blk = bid - b * 22;
  int base0 = blk * 192;
  int t = threadIdx.x;

  // stage x slab
  const float* xb = x + (size_t)b * DIN * L_;
  for (int q = t; q < DIN * 195; q += 256) {
    int i = q / 195, c = q - i * 195;
    int nx = base0 - 1 + c;
    xs[q] = (nx >= 0 && nx < L_) ? xb[i * L_ + nx] : 0.f;
  }
  // u-prep: wave w covers d in [w*128, w*128+128); lane indexes cw row (coalesced 256B)
  {
    int lane = t & 63, wv = t >> 6;
    float ua = 0.f, ca = 0.f;
    for (int d = wv * 128; d < wv * 128 + 128; ++d) {
      ua = fmaf(sw[d], cw[((size_t)d << 6) + lane], ua);
      ca = fmaf(sw[d], cb[d], ca);
    }
    ured[wv][lane] = ua;
    if (lane == 0) ured[wv][64] = ca;
  }
  __syncthreads();
  if (t < 65) ul[t] = ured[0][t] + ured[1][t] + ured[2][t] + ured[3][t];
  __syncthreads();

  // t-values
  if (t < 192) {
    int n = base0 + t;
    float tv = 0.f;
    if (n < L_) {
      tv = ul[64];
      for (int i = 0; i < DIN; ++i) {
#pragma unroll
        for (int k = 0; k < 4; ++k)
          tv = fmaf(xs[i * 195 + t + k], ul[(i << 2) + k], tv);
      }
    }
    tb[t] = tv;
  }
  __syncthreads();

  // softmax over m; stash f32 rows + logs for the moment phase
  if (t < 192) {
    int n = base0 + t;
    if (n < NP) {
      float t1 = tb[t];
      int e2 = t & ~1;
      float t2 = 0.5f * (tb[e2] + tb[e2 + 1]);
      int e3 = (t / 3) * 3;
      float t3 = (1.f / 3.f) * (tb[e3] + tb[e3 + 1] + tb[e3 + 2]);
      int e4 = t & ~3;
      float t4 = 0.25f * (tb[e4] + tb[e4 + 1] + tb[e4 + 2] + tb[e4 + 3]);
      float sbv = sb[0];
      float c0s = t1 + sbv, c1s = t2 + sbv, c2s = t3 + sbv, c3s = t4 + sbv;
      float mx = fmaxf(fmaxf(c0s, c1s), fmaxf(c2s, c3s));
      float e0 = __expf(c0s - mx), e1 = __expf(c1s - mx);
      float e2f = __expf(c2s - mx), e3f = __expf(c3s - mx);
      float inv = 1.f / (e0 + e1 + e2f + e3f);
      float v0 = e0 * inv, v1 = e1 * inv, v2 = e2f * inv, v3 = e3f * inv;
      ushort4 ov;
      ov.x = f2bf(v0); ov.y = f2bf(v1); ov.z = f2bf(v2); ov.w = f2bf(v3);
      *reinterpret_cast<ushort4*>(&s0[(((size_t)b * NP) + n) << 2]) = ov;
      sval[t][0] = v0; sval[t][1] = v1; sval[t][2] = v2; sval[t][3] = v3;
      sval[t][4] = 1.f;
      lsv[t][0] = __log2f(v0); lsv[t][1] = __log2f(v1);
      lsv[t][2] = __log2f(v2); lsv[t][3] = __log2f(v3);
    } else {
      sval[t][0] = 0.f; sval[t][1] = 0.f; sval[t][2] = 0.f;
      sval[t][3] = 0.f; sval[t][4] = 0.f;
      lsv[t][0] = 0.f; lsv[t][1] = 0.f; lsv[t][2] = 0.f; lsv[t][3] = 0.f;
    }
  }
  __syncthreads();

  // moment partials: threads 0..125 -> rows 0..95; threads 128..253 -> rows 96..191
  int half = (t >= 128) ? 1 : 0;
  int f = t - half * 128;
  if (f < 126) {
    int fa = 0, fb = 0, fc = 0, fd = 0;
    {
      int ff = 0;
      for (int a = 0; a <= 5; ++a)
        for (int b2 = 0; b2 <= 5 - a; ++b2)
          for (int cc = 0; cc <= 5 - a - b2; ++cc)
            for (int d2 = 0; d2 <= 5 - a - b2 - cc; ++d2) {
              if (ff == f) { fa = a; fb = b2; fc = cc; fd = d2; }
              ++ff;
            }
    }
    float ea = (float)fa, eb = (float)fb, ec = (float)fc, ed = (float)fd;
    int k = fa + fb + fc + fd;
    float w = D5[k] * FACT[k] / (FACT[fa] * FACT[fb] * FACT[fc] * FACT[fd]);
    float a0 = 0.f, a1 = 0.f, a2 = 0.f, a3 = 0.f, a4 = 0.f;
    int r0 = half * 96;
    for (int r = r0; r < r0 + 96; ++r) {
      float4 lv = *reinterpret_cast<const float4*>(&lsv[r][0]);
      float dot = ea * lv.x;
      dot = fmaf(eb, lv.y, dot);
      dot = fmaf(ec, lv.z, dot);
      dot = fmaf(ed, lv.w, dot);
      float m = exp2f(dot);
      a0 = fmaf(m, sval[r][0], a0);
      a1 = fmaf(m, sval[r][1], a1);
      a2 = fmaf(m, sval[r][2], a2);
      a3 = fmaf(m, sval[r][3], a3);
      a4 = fmaf(m, sval[r][4], a4);
    }
    size_t pbase = ((size_t)(b * NCH + blk * 2 + half)) * 640 + f * 5;
    Mpart[pbase + 0] = w * a0;
    Mpart[pbase + 1] = w * a1;
    Mpart[pbase + 2] = w * a2;
    Mpart[pbase + 3] = w * a3;
    Mpart[pbase + 4] = w * a4;
  }
}

// ---------------- Kernel 2: apply (reduces 44 weighted partials in-block) -> s2 ----------------
__global__ __launch_bounds__(256) void k_apply(
    const unsigned short* __restrict__ s0, const float* __restrict__ Mpart,
    float* __restrict__ s2) {
  __shared__ float M[128 * 8];
  int bid = blockIdx.x;
  int b = bid / 17, ch = bid - b * 17;
  int t = threadIdx.x;
  for (int e = t; e < 630; e += 256) {
    float s = 0.f;
#pragma unroll 4
    for (int c2 = 0; c2 < NCH; ++c2)
      s += Mpart[((size_t)(b * NCH + c2)) * 640 + e];
    int f = e / 5, c = e - f * 5;
    M[f * 8 + c] = s;
  }
  __syncthreads();
  int i = ch * 256 + t;
  if (i >= NP) return;
  ushort4 u = reinterpret_cast<const ushort4*>(s0)[(size_t)b * NP + i];
  float s_0 = bf2f(u.x), s_1 = bf2f(u.y), s_2 = bf2f(u.z), s_3 = bf2f(u.w);
  float a0 = 0.f, a1 = 0.f, a2 = 0.f, a3 = 0.f, az = 0.f;
  int f = 0;
  float pa = 1.f;
#pragma unroll
  for (int a = 0; a <= 5; ++a) {
    float pb = pa;
#pragma unroll
    for (int b2 = 0; b2 <= 5 - a; ++b2) {
      float pc = pb;
#pragma unroll
      for (int c = 0; c <= 5 - a - b2; ++c) {
        float run = pc;
#pragma unroll
        for (int d2 = 0; d2 <= 5 - a - b2 - c; ++d2) {
          const float* mf = &M[f * 8];
          float4 m4 = *reinterpret_cast<const float4*>(mf);
          a0 = fmaf(run, m4.x, a0);
          a1 = fmaf(run, m4.y, a1);
          a2 = fmaf(run, m4.z, a2);
          a3 = fmaf(run, m4.w, a3);
          az = fmaf(run, mf[4], az);
          run *= s_3;
          ++f;
        }
        pc *= s_2;
      }
      pb *= s_1;
    }
    pa *= s_0;
  }
  float inv = 1.f / az;
  reinterpret_cast<float4*>(s2)[(size_t)b * NP + i] =
      make_float4(a0 * inv, a1 * inv, a2 * inv, a3 * inv);
}

// ---------------- Kernel 3: fused conv + pooled-combine -> outputs (round-13 exact) ----------------
__global__ __launch_bounds__(256, 4) void k_fused(
    const float* __restrict__ x, const float* __restrict__ cw,
    const float* __restrict__ cb, const float* __restrict__ s2,
    float* __restrict__ out) {
  __shared__ float ws_w[32 * 132];      // 16896 B
  __shared__ float ws_x[DIN * XSTR];    // 6656 B
  __shared__ float ss[8][12][4];        // 1536 B
  int bid = blockIdx.x;
  int dtile = bid & 7;
  int span = (bid >> 3) % NSPAN2;
  int b = bid / (8 * NSPAN2);
  int n0 = span * SPAN2;
  int d0 = dtile * 64;
  int g0 = n0 / 12;
  int tid = threadIdx.x;

  for (int q = tid; q < 64 * 16; q += 256) {
    int dd = q >> 4, qq = (q & 15) << 2;
    float4 wv = *reinterpret_cast<const float4*>(cw + ((size_t)(d0 + dd) << 6) + qq);
    *reinterpret_cast<float4*>(&ws_w[(dd >> 1) * 132 + (dd & 1) * 64 + qq]) = wv;
  }
  const float* xb = x + (size_t)b * DIN * L_;
  for (int q = tid; q < DIN * XSTR; q += 256) {
    int i = q / XSTR, c = q - i * XSTR;
    int nx = n0 - 1 + c;
    ws_x[q] = (c < 99 && nx >= 0 && nx < L_) ? xb[i * L_ + nx] : 0.f;
  }
  for (int q = tid; q < 384; q += 256) {
    int gg = q / 48, r = q - gg * 48;
    int g = g0 + gg;
    ((float*)ss)[q] = (g < NG) ? s2[((size_t)b * NP + g * 12) * 4 + r] : 0.f;
  }
  __syncthreads();

  int dp = tid & 31;
  int seg = tid >> 5;
  int g = g0 + seg;
  float acc0[12], acc1[12];
#pragma unroll
  for (int j = 0; j < 12; ++j) { acc0[j] = 0.f; acc1[j] = 0.f; }

  for (int i = 0; i < DIN; ++i) {
    const float* wp = &ws_w[dp * 132 + (i << 2)];
    float4 wv0 = *reinterpret_cast<const float4*>(wp);
    float4 wv1 = *reinterpret_cast<const float4*>(wp + 64);
    const float* xp = &ws_x[i * XSTR + seg * 12];
    float4 xv0 = *reinterpret_cast<const float4*>(xp);
    float4 xv1 = *reinterpret_cast<const float4*>(xp + 4);
    float4 xv2 = *reinterpret_cast<const float4*>(xp + 8);
    float4 xv3 = *reinterpret_cast<const float4*>(xp + 12);
    float xr[16] = {xv0.x, xv0.y, xv0.z, xv0.w, xv1.x, xv1.y, xv1.z, xv1.w,
                    xv2.x, xv2.y, xv2.z, xv2.w, xv3.x, xv3.y, xv3.z, xv3.w};
#pragma unroll
    for (int j = 0; j < 12; ++j) {
      float a0 = acc0[j], a1 = acc1[j];
      a0 = fmaf(wv0.x, xr[j], a0);
      a0 = fmaf(wv0.y, xr[j + 1], a0);
      a0 = fmaf(wv0.z, xr[j + 2], a0);
      a0 = fmaf(wv0.w, xr[j + 3], a0);
      a1 = fmaf(wv1.x, xr[j], a1);
      a1 = fmaf(wv1.y, xr[j + 1], a1);
      a1 = fmaf(wv1.z, xr[j + 2], a1);
      a1 = fmaf(wv1.w, xr[j + 3], a1);
      acc0[j] = a0; acc1[j] = a1;
    }
  }
  if (g >= NG) return;

  int d = d0 + (dp << 1);
  float cb0 = cb[d], cb1 = cb[d + 1];
  int base = g * 12;
  float hv0[12], hv1[12];
#pragma unroll
  for (int j = 0; j < 12; ++j) {
    int n = base + j;
    if (n < L_) { hv0[j] = acc0[j] + cb0; hv1[j] = acc1[j] + cb1; }
    else { hv0[j] = 0.f; hv1[j] = 0.f; }
  }
  float P20[6], P21[6], P30[4], P31[4], P40[3], P41[3];
#pragma unroll
  for (int q = 0; q < 6; ++q) {
    P20[q] = 0.5f * (hv0[2 * q] + hv0[2 * q + 1]);
    P21[q] = 0.5f * (hv1[2 * q] + hv1[2 * q + 1]);
  }
#pragma unroll
  for (int q = 0; q < 4; ++q) {
    P30[q] = (1.f / 3.f) * (hv0[3 * q] + hv0[3 * q + 1] + hv0[3 * q + 2]);
    P31[q] = (1.f / 3.f) * (hv1[3 * q] + hv1[3 * q + 1] + hv1[3 * q + 2]);
  }
#pragma unroll
  for (int q = 0; q < 3; ++q) {
    P40[q] = 0.25f * (hv0[4 * q] + hv0[4 * q + 1] + hv0[4 * q + 2] + hv0[4 * q + 3]);
    P41[q] = 0.25f * (hv1[4 * q] + hv1[4 * q + 1] + hv1[4 * q + 2] + hv1[4 * q + 3]);
  }
  float* outc = out;
  float* outd = out + (size_t)B_ * L_ * D_;
  float xq0[3] = {0.f, 0.f, 0.f}, xq1[3] = {0.f, 0.f, 0.f};
#pragma unroll
  for (int j = 0; j < 12; ++j) {
    float w0 = ss[seg][j][0], w1 = ss[seg][j][1];
    float w2 = ss[seg][j][2], w3 = ss[seg][j][3];
    float v0 = w0 * hv0[j] + w1 * P20[j >> 1] + w2 * P30[j / 3] + w3 * P40[j >> 2];
    float v1 = w0 * hv1[j] + w1 * P21[j >> 1] + w2 * P31[j / 3] + w3 * P41[j >> 2];
    int n = base + j;
    if (n < L_) {
      float2 o; o.x = v0; o.y = v1;
      *reinterpret_cast<float2*>(&outc[((size_t)b * L_ + n) * D_ + d]) = o;
    }
    xq0[j >> 2] += v0; xq1[j >> 2] += v1;
  }
#pragma unroll
  for (int q = 0; q < 3; ++q) {
    int r = 3 * g + q;
    if (r < 1024) {
      float2 o; o.x = 0.25f * xq0[q]; o.y = 0.25f * xq1[q];
      *reinterpret_cast<float2*>(&outd[((size_t)b * 1024 + r) * D_ + d]) = o;
    }
  }
}

extern "C" void kernel_launch(void* const* d_in, const int* in_sizes, int n_in,
                              void* d_out, int out_size, void* d_ws, size_t ws_size,
                              hipStream_t stream) {
  const float* x = (const float*)d_in[0];
  const float* cw = (const float*)d_in[1];
  const float* cb = (const float*)d_in[2];
  const float* sw = (const float*)d_in[3];
  const float* sb = (const float*)d_in[4];
  float* out = (float*)d_out;
  char* ws = (char*)d_ws;
  size_t off = 0;
  unsigned short* s0 = (unsigned short*)(ws + off);        // 262,656 B
  off += 262656;
  float* s2 = (float*)(ws + off);                          // 525,312 B
  off += 525312;
  float* Mpart = (float*)(ws + off);                       // 8*44*640*4 = 901,120 B
  off += 901120;

  k_scores2<<<8 * 22, 256, 0, stream>>>(x, cw, cb, sw, sb, s0, Mpart);
  k_apply<<<8 * 17, 256, 0, stream>>>(s0, Mpart, s2);
  k_fused<<<B_ * NSPAN2 * 8, 256, 0, stream>>>(x, cw, cb, s2, out);
}